// Round 1
// baseline (562.199 us; speedup 1.0000x reference)
//
#include <hip/hip_runtime.h>
#include <hip/hip_bf16.h>
#include <math.h>

typedef __hip_bfloat16 bf16;
typedef __attribute__((ext_vector_type(8))) short short8;
typedef __attribute__((ext_vector_type(4))) float f32x4;

__device__ __forceinline__ float elu_f(float x){ return x > 0.f ? x : expm1f(x); }
__device__ __forceinline__ float b2f(unsigned short u){ return __uint_as_float(((unsigned)u) << 16); }
__device__ __forceinline__ unsigned short f2b(float f){ bf16 h = __float2bfloat16(f); return *reinterpret_cast<unsigned short*>(&h); }

// ---------- dtype detection (parallel) ----------
__global__ __launch_bounds__(256) void detect_part_kernel(const unsigned* __restrict__ ei_u, int twoE_words,
                                                          const unsigned* __restrict__ x_u, int min_xwords,
                                                          int* __restrict__ raw){
    __shared__ int sd[256];
    __shared__ int sc[256];
    int tid = threadIdx.x;
    int gid = blockIdx.x*256 + tid;
    long long pairs = twoE_words/2;

    int orv = 0;
    if (gid < 16384 && pairs > 0){
        long long idx = ((long long)gid * pairs) / 16384;
        long long w = 2*idx + 1;
        if (w < twoE_words) orv = (int)ei_u[w];
    }
    int cnt = 0;
    int s = gid - 16384;
    if (s >= 0 && s < 4096){
        long long idx = ((long long)s * min_xwords) / 4096;
        if (idx < min_xwords){
            unsigned e = (x_u[idx] >> 7) & 0xFFu;
            cnt = (e >= 96u && e <= 160u) ? 1 : 0;
        }
    }
    sd[tid] = orv; sc[tid] = cnt;
    __syncthreads();
    #pragma unroll
    for (int off = 128; off > 0; off >>= 1){
        if (tid < off){ sd[tid] |= sd[tid+off]; sc[tid] += sc[tid+off]; }
        __syncthreads();
    }
    if (tid == 0){
        if (sd[0]) atomicOr(&raw[0], sd[0]);
        if (sc[0]) atomicAdd(&raw[1], sc[0]);
    }
}

__global__ void finalize_kernel(const int* __restrict__ raw, int* __restrict__ flags){
    flags[0] = (raw[0] == 0) ? 1 : 0;
    flags[1] = (raw[1]*2 > 4096) ? 1 : 0;
}

__device__ __forceinline__ int load_src(const int* ei, int e, int E, int is64){
    return is64 ? ei[2*e] : ei[e];
}
__device__ __forceinline__ int load_dst(const int* ei, int e, int E, int is64){
    return is64 ? ei[2*(E + e)] : ei[E + e];
}
__device__ __forceinline__ float loadf(const void* base, size_t idx, int isbf){
    return isbf ? __bfloat162float(((const bf16*)base)[idx]) : ((const float*)base)[idx];
}

// ---------- CSR build ----------
__global__ void count_kernel(const int* __restrict__ ei, const int* __restrict__ flags,
                             int* __restrict__ counts, int E, int N){
    int e = blockIdx.x*256 + threadIdx.x;
    if (e < E){
        int d = load_dst(ei, e, E, flags[0]);
        if ((unsigned)d < (unsigned)N) atomicAdd(&counts[d], 1);
    }
}

__global__ void dinv_kernel(const int* __restrict__ counts, float* __restrict__ dinv, int N){
    int n = blockIdx.x*256 + threadIdx.x;
    if (n < N){
        double d = (double)(counts[n] + 1);
        if (d < 1.0) d = 1.0;
        dinv[n] = (float)(1.0 / sqrt(d));
    }
}

__global__ void partial_kernel(const int* __restrict__ counts, int* __restrict__ partial, int N){
    __shared__ int sd[256];
    int tid = threadIdx.x;
    int i = blockIdx.x*256 + tid;
    sd[tid] = (i < N) ? counts[i] : 0;
    __syncthreads();
    #pragma unroll
    for (int off = 128; off > 0; off >>= 1){
        if (tid < off) sd[tid] += sd[tid+off];
        __syncthreads();
    }
    if (tid == 0) partial[blockIdx.x] = sd[0];
}

__global__ void scanp_kernel(const int* __restrict__ partial, int* __restrict__ blockoff, int nb){
    __shared__ int sd[256];
    int tid = threadIdx.x;
    int v = (tid < nb) ? partial[tid] : 0;
    sd[tid] = v;
    __syncthreads();
    #pragma unroll
    for (int off = 1; off < 256; off <<= 1){
        int t = (tid >= off) ? sd[tid-off] : 0;
        __syncthreads();
        sd[tid] += t;
        __syncthreads();
    }
    if (tid < nb) blockoff[tid] = sd[tid] - v;
}

__global__ void offsets_kernel(const int* __restrict__ counts, const int* __restrict__ blockoff,
                               int* __restrict__ offsets, int* __restrict__ cursor, int N){
    __shared__ int sd[256];
    int tid = threadIdx.x;
    int i = blockIdx.x*256 + tid;
    int v = (i < N) ? counts[i] : 0;
    sd[tid] = v;
    __syncthreads();
    #pragma unroll
    for (int off = 1; off < 256; off <<= 1){
        int t = (tid >= off) ? sd[tid-off] : 0;
        __syncthreads();
        sd[tid] += t;
        __syncthreads();
    }
    if (i < N){
        int o = blockoff[blockIdx.x] + sd[tid] - v;
        offsets[i] = o;
        cursor[i]  = o;
    }
}

__global__ void scatter_kernel(const int* __restrict__ ei, const int* __restrict__ flags,
                               int* __restrict__ cursor, int* __restrict__ csr, int E, int N){
    int e = blockIdx.x*256 + threadIdx.x;
    if (e < E){
        int is64 = flags[0];
        int d = load_dst(ei, e, E, is64);
        int s = load_src(ei, e, E, is64);
        if ((unsigned)d < (unsigned)N){
            int pos = atomicAdd(&cursor[d], 1);
            if ((unsigned)pos < (unsigned)E) csr[pos] = s;
        }
    }
}

// ---------- W^T build (bf16 path only): WT[l][c*128 + k] = W[l][k*128 + c] ----------
__global__ __launch_bounds__(256) void wt_all_kernel(const void* __restrict__ W0, const void* __restrict__ W1,
                                                     const void* __restrict__ W2, const void* __restrict__ W3,
                                                     const int* __restrict__ flags, unsigned short* __restrict__ WT){
    if (!flags[1]) return;
    const unsigned short* src = (const unsigned short*)(blockIdx.x == 0 ? W0 :
                                blockIdx.x == 1 ? W1 : blockIdx.x == 2 ? W2 : W3);
    unsigned short* dst = WT + (size_t)blockIdx.x*16384;
    for (int i = threadIdx.x; i < 16384; i += 256){
        int k = i >> 7, c = i & 127;
        dst[c*128 + k] = src[i];
    }
}

// ---------- MFMA GEMM (bf16 path): Y[N,128] = X[N,128] @ W[128,128], bf16 in/out, fp32 accum.
// Verified recipe (learn_hip m92/m97): row-major A tile + B^T tile in LDS; fragment = 8
// contiguous k per lane at row (lane&15), k-block 8*(lane>>4); C/D: col=lane&15, row=4*(lane>>4)+reg.
__global__ __launch_bounds__(256) void gemm_mfma_kernel(const void* __restrict__ X, const unsigned short* __restrict__ WT,
                                                        const int* __restrict__ flags, void* __restrict__ Y, int N){
    if (!flags[1]) return;
    __shared__ __align__(16) unsigned short xs[64*136];   // 64 rows x 128 (+8 pad)
    __shared__ __align__(16) unsigned short wt[128*136];  // 128 cols-of-W as rows x 128 k (+8 pad)
    int tid = threadIdx.x;
    int r0 = blockIdx.x * 64;

    {   // stage W^T: 32KB, 128B per thread
        int r = tid >> 1, half = tid & 1;
        const float4* src = (const float4*)WT;
        #pragma unroll
        for (int i = 0; i < 8; i++){
            float4 v = src[r*16 + half*8 + i];
            *(float4*)&wt[r*136 + (half*8 + i)*8] = v;
        }
    }
    {   // stage X tile: 64 rows x 256B, 64B per thread
        int r = tid >> 2, sgm = tid & 3;
        const float4* src = (const float4*)X;
        #pragma unroll
        for (int i = 0; i < 4; i++){
            float4 u = make_float4(0.f, 0.f, 0.f, 0.f);
            if (r0 + r < N) u = src[(size_t)(r0 + r)*16 + sgm*4 + i];
            *(float4*)&xs[r*136 + (sgm*4 + i)*8] = u;
        }
    }
    __syncthreads();

    int w = tid >> 6, lane = tid & 63;
    int lq = lane & 15, lh = lane >> 4;
    const unsigned short* arow = &xs[(w*16 + lq)*136 + lh*8];

    f32x4 acc[8];
    #pragma unroll
    for (int i = 0; i < 8; i++){
        #pragma unroll
        for (int e = 0; e < 4; e++) acc[i][e] = 0.f;
    }

    #pragma unroll
    for (int k0 = 0; k0 < 4; k0++){
        short8 a = *reinterpret_cast<const short8*>(arow + k0*32);
        #pragma unroll
        for (int nt = 0; nt < 8; nt++){
            short8 b = *reinterpret_cast<const short8*>(&wt[(nt*16 + lq)*136 + k0*32 + lh*8]);
            acc[nt] = __builtin_amdgcn_mfma_f32_16x16x32_bf16(a, b, acc[nt], 0, 0, 0);
        }
    }

    bf16* Yb = (bf16*)Y;
    #pragma unroll
    for (int nt = 0; nt < 8; nt++){
        #pragma unroll
        for (int i = 0; i < 4; i++){
            int row = r0 + w*16 + lh*4 + i;
            if (row < N) Yb[(size_t)row*128 + nt*16 + lq] = __float2bfloat16(acc[nt][i]);
        }
    }
}

// ---------- scalar GEMM (fp32 fallback path only) ----------
__global__ __launch_bounds__(256) void gemm_kernel(const void* __restrict__ X, const void* __restrict__ Wv,
                                                   const int* __restrict__ flags,
                                                   void* __restrict__ Y, int N){
    if (flags[1]) return;   // bf16 handled by gemm_mfma_kernel
    __shared__ float xs[32][132];
    int tid = threadIdx.x;
    int r0 = blockIdx.x * 32;

    for (int i = tid; i < 1024; i += 256){
        int r = i >> 5, k4 = i & 31;
        float4 v = make_float4(0.f, 0.f, 0.f, 0.f);
        if (r0 + r < N) v = ((const float4*)X)[(size_t)(r0 + r)*32 + k4];
        *(float4*)&xs[r][k4*4] = v;
    }
    __syncthreads();

    int rg = tid >> 6;
    float acc0[8], acc1[8];
    #pragma unroll
    for (int i = 0; i < 8; i++){ acc0[i] = 0.f; acc1[i] = 0.f; }

    int cp = tid & 63;
    const float* W = (const float*)Wv;
    for (int k0 = 0; k0 < 128; k0 += 4){
        float wa0 = W[(k0+0)*128 + cp];
        float wa1 = W[(k0+1)*128 + cp];
        float wa2 = W[(k0+2)*128 + cp];
        float wa3 = W[(k0+3)*128 + cp];
        float wb0 = W[(k0+0)*128 + cp + 64];
        float wb1 = W[(k0+1)*128 + cp + 64];
        float wb2 = W[(k0+2)*128 + cp + 64];
        float wb3 = W[(k0+3)*128 + cp + 64];
        #pragma unroll
        for (int rr = 0; rr < 8; rr++){
            float4 xv = *(const float4*)&xs[rg*8 + rr][k0];
            acc0[rr] += xv.x*wa0; acc0[rr] += xv.y*wa1; acc0[rr] += xv.z*wa2; acc0[rr] += xv.w*wa3;
            acc1[rr] += xv.x*wb0; acc1[rr] += xv.y*wb1; acc1[rr] += xv.z*wb2; acc1[rr] += xv.w*wb3;
        }
    }
    #pragma unroll
    for (int rr = 0; rr < 8; rr++){
        int r = r0 + rg*8 + rr;
        if (r < N){
            ((float*)Y)[(size_t)r*128 + cp]      = acc0[rr];
            ((float*)Y)[(size_t)r*128 + cp + 64] = acc1[rr];
        }
    }
}

// ---------- aggregation: one wave per dst row. bf16 path: 8B/lane (4 feats), half-wave
// pairs -> 2 neighbor rows per VMEM instr, 8 edges (2KB) in flight per unrolled iter.
__global__ __launch_bounds__(256) void agg_kernel(const void* __restrict__ XW, const float* __restrict__ dinv,
                                                  const int* __restrict__ offsets, const int* __restrict__ counts,
                                                  const int* __restrict__ csr, const void* __restrict__ bias,
                                                  void* __restrict__ Hout, const int* __restrict__ flags, int N){
    int wave = threadIdx.x >> 6;
    int lane = threadIdx.x & 63;
    int n = blockIdx.x*4 + wave;
    if (n >= N) return;
    int isbf = flags[1];

    float dn = dinv[n];
    float sw = dn*dn;

    if (isbf){
        int h = lane >> 5, q = lane & 31;   // lane handles features 4q..4q+3; halves split edges
        const ushort4* X4 = (const ushort4*)XW;
        float a0, a1, a2, a3;
        if (h == 0){
            ushort4 v = X4[(size_t)n*32 + q];
            a0 = b2f(v.x)*sw; a1 = b2f(v.y)*sw; a2 = b2f(v.z)*sw; a3 = b2f(v.w)*sw;
        } else { a0 = a1 = a2 = a3 = 0.f; }

        int j0 = offsets[n], cnt = counts[n];
        for (int base = 0; base < cnt; base += 64){
            int m = cnt - base; if (m > 64) m = 64;
            int s_l = 0; float w_l = 0.f;
            if (lane < m){
                int s = csr[j0 + base + lane];
                if ((unsigned)s < (unsigned)N){ s_l = s; w_l = dinv[s]*dn; }
            }
            int j = 0;
            for (; j + 8 <= m; j += 8){
                int   s0 = __shfl(s_l, j + h),     s1 = __shfl(s_l, j + 2 + h);
                int   s2 = __shfl(s_l, j + 4 + h), s3 = __shfl(s_l, j + 6 + h);
                float w0 = __shfl(w_l, j + h),     w1 = __shfl(w_l, j + 2 + h);
                float w2 = __shfl(w_l, j + 4 + h), w3 = __shfl(w_l, j + 6 + h);
                ushort4 u0 = X4[(size_t)s0*32 + q];
                ushort4 u1 = X4[(size_t)s1*32 + q];
                ushort4 u2 = X4[(size_t)s2*32 + q];
                ushort4 u3 = X4[(size_t)s3*32 + q];
                a0 += b2f(u0.x)*w0; a1 += b2f(u0.y)*w0; a2 += b2f(u0.z)*w0; a3 += b2f(u0.w)*w0;
                a0 += b2f(u1.x)*w1; a1 += b2f(u1.y)*w1; a2 += b2f(u1.z)*w1; a3 += b2f(u1.w)*w1;
                a0 += b2f(u2.x)*w2; a1 += b2f(u2.y)*w2; a2 += b2f(u2.z)*w2; a3 += b2f(u2.w)*w2;
                a0 += b2f(u3.x)*w3; a1 += b2f(u3.y)*w3; a2 += b2f(u3.z)*w3; a3 += b2f(u3.w)*w3;
            }
            for (; j < m; j += 2){
                // odd tail: half 1 reads lane index == m, whose prefetch is (0, 0.f) -> contributes 0
                int   s = __shfl(s_l, j + h);
                float w = __shfl(w_l, j + h);
                ushort4 u = X4[(size_t)s*32 + q];
                a0 += b2f(u.x)*w; a1 += b2f(u.y)*w; a2 += b2f(u.z)*w; a3 += b2f(u.w)*w;
            }
        }
        a0 += __shfl_xor(a0, 32);
        a1 += __shfl_xor(a1, 32);
        a2 += __shfl_xor(a2, 32);
        a3 += __shfl_xor(a3, 32);
        if (h == 0){
            a0 = elu_f(a0 + loadf(bias, 4*q + 0, 1));
            a1 = elu_f(a1 + loadf(bias, 4*q + 1, 1));
            a2 = elu_f(a2 + loadf(bias, 4*q + 2, 1));
            a3 = elu_f(a3 + loadf(bias, 4*q + 3, 1));
            ushort4 o;
            o.x = f2b(a0); o.y = f2b(a1); o.z = f2b(a2); o.w = f2b(a3);
            ((ushort4*)Hout)[(size_t)n*32 + q] = o;
        }
    } else {
        float accx, accy;
        float2 v = ((const float2*)XW)[(size_t)n*64 + lane];
        accx = v.x*sw; accy = v.y*sw;

        int j0 = offsets[n], cnt = counts[n];
        for (int base = 0; base < cnt; base += 64){
            int m = cnt - base; if (m > 64) m = 64;
            int s_l = 0; float w_l = 0.f;
            if (lane < m){
                int s = csr[j0 + base + lane];
                if ((unsigned)s < (unsigned)N){ s_l = s; w_l = dinv[s]*dn; }
            }
            int j = 0;
            const float2* XF = (const float2*)XW;
            for (; j + 4 <= m; j += 4){
                int   s0 = __shfl(s_l, j),   s1 = __shfl(s_l, j+1), s2 = __shfl(s_l, j+2), s3 = __shfl(s_l, j+3);
                float w0 = __shfl(w_l, j),   w1 = __shfl(w_l, j+1), w2 = __shfl(w_l, j+2), w3 = __shfl(w_l, j+3);
                float2 u0 = XF[(size_t)s0*64 + lane];
                float2 u1 = XF[(size_t)s1*64 + lane];
                float2 u2 = XF[(size_t)s2*64 + lane];
                float2 u3 = XF[(size_t)s3*64 + lane];
                accx += u0.x*w0; accy += u0.y*w0;
                accx += u1.x*w1; accy += u1.y*w1;
                accx += u2.x*w2; accy += u2.y*w2;
                accx += u3.x*w3; accy += u3.y*w3;
            }
            for (; j < m; ++j){
                int   s = __shfl(s_l, j);
                float w = __shfl(w_l, j);
                float2 u = XF[(size_t)s*64 + lane];
                accx += u.x*w; accy += u.y*w;
            }
        }

        accx = elu_f(accx + loadf(bias, lane*2,     0));
        accy = elu_f(accy + loadf(bias, lane*2 + 1, 0));
        *(float2*)((float*)Hout + (size_t)n*128 + lane*2) = make_float2(accx, accy);
    }
}

// ---------- MLP head (only Wm2/bm2 survive the reference's reassignment bug) ----------
__global__ __launch_bounds__(256) void mlp_kernel(void* __restrict__ dout, const void* __restrict__ Wm,
                                                  const void* __restrict__ bm, const int* __restrict__ flags, int N){
    __shared__ float ws_[1280];
    __shared__ __align__(16) unsigned short hs[16*136];
    int tid = threadIdx.x;
    int isbf = flags[1];
    for (int i = tid; i < 1280; i += 256) ws_[i] = loadf(Wm, i, isbf);

    int r = tid >> 4, c = tid & 15;
    int row = blockIdx.x*16 + r;
    if (isbf){
        if (row < N){
            float4 v = ((const float4*)dout)[(size_t)row*16 + c];
            *(float4*)&hs[r*136 + c*8] = v;
        }
        __syncthreads();
        if (row < N && c < 10){
            float acc = 0.f;
            #pragma unroll 8
            for (int k = 0; k < 128; k += 4){
                ushort4 h4 = *(const ushort4*)&hs[r*136 + k];
                acc += b2f(h4.x)*ws_[(k+0)*10 + c];
                acc += b2f(h4.y)*ws_[(k+1)*10 + c];
                acc += b2f(h4.z)*ws_[(k+2)*10 + c];
                acc += b2f(h4.w)*ws_[(k+3)*10 + c];
            }
            acc += loadf(bm, c, 1);
            ((bf16*)dout)[(size_t)N*128 + (size_t)row*10 + c] = __float2bfloat16(elu_f(acc));
        }
    } else {
        __syncthreads();
        if (row < N && c < 10){
            const float* hr = (const float*)dout + (size_t)row*128;
            float acc = 0.f;
            #pragma unroll 8
            for (int k = 0; k < 128; k++) acc += hr[k]*ws_[k*10 + c];
            acc += loadf(bm, c, 0);
            ((float*)dout)[(size_t)N*128 + (size_t)row*10 + c] = elu_f(acc);
        }
    }
}

static inline char* alignup(char* p, size_t a){ return (char*)(((uintptr_t)p + a - 1) & ~(a - 1)); }

extern "C" void kernel_launch(void* const* d_in, const int* in_sizes, int n_in,
                              void* d_out, int out_size, void* d_ws, size_t ws_size,
                              hipStream_t stream){
    const void* x  = d_in[0];
    const int*  ei = (const int*)d_in[1];
    const void* W[4] = {d_in[2], d_in[4], d_in[6], d_in[8]};
    const void* B[4] = {d_in[3], d_in[5], d_in[7], d_in[9]};
    const void* Wm2 = d_in[12];
    const void* bm2 = d_in[13];

    int N = in_sizes[0] / 128;
    int E = in_sizes[1] / 2;

    char* p = (char*)d_ws;
    int*   flags    = (int*)p;
    int*   raw      = flags + 2;                   p = alignup(p + 4*sizeof(int), 256);
    float* dinv     = (float*)p;                   p = alignup(p + (size_t)N*4, 256);
    int*   counts   = (int*)p;                     p = alignup(p + (size_t)N*4, 256);
    int*   offsets  = (int*)p;                     p = alignup(p + (size_t)N*4, 256);
    int*   cursor   = (int*)p;                     p = alignup(p + (size_t)N*4, 256);
    int*   partial  = (int*)p;                     p = alignup(p + 256*4, 256);
    int*   blockoff = (int*)p;                     p = alignup(p + 256*4, 256);
    int*   csr      = (int*)p;                     p = alignup(p + (size_t)E*4, 256);
    void*  xw       = (void*)p;                    p = alignup(p + (size_t)N*128*4, 256);
    unsigned short* WTbuf = (unsigned short*)p;    p = alignup(p + (size_t)4*16384*2, 256);

    int nb = (N + 255)/256;

    hipMemsetAsync(flags, 0, 4*sizeof(int), stream);
    hipMemsetAsync(counts, 0, (size_t)N*sizeof(int), stream);
    detect_part_kernel<<<128, 256, 0, stream>>>((const unsigned*)ei, 2*E, (const unsigned*)x, N*128/2, raw);
    finalize_kernel   <<<1, 1, 0, stream>>>(raw, flags);
    wt_all_kernel <<<4, 256, 0, stream>>>(W[0], W[1], W[2], W[3], flags, WTbuf);
    count_kernel  <<<(E + 255)/256, 256, 0, stream>>>(ei, flags, counts, E, N);
    dinv_kernel   <<<nb, 256, 0, stream>>>(counts, dinv, N);
    partial_kernel<<<nb, 256, 0, stream>>>(counts, partial, N);
    scanp_kernel  <<<1, 256, 0, stream>>>(partial, blockoff, nb);
    offsets_kernel<<<nb, 256, 0, stream>>>(counts, blockoff, offsets, cursor, N);
    scatter_kernel<<<(E + 255)/256, 256, 0, stream>>>(ei, flags, cursor, csr, E, N);

    for (int l = 0; l < 4; ++l){
        const void* Xin = (l == 0) ? x : (const void*)d_out;
        gemm_mfma_kernel<<<(N + 63)/64, 256, 0, stream>>>(Xin, WTbuf + (size_t)l*16384, flags, xw, N);
        gemm_kernel     <<<(N + 31)/32, 256, 0, stream>>>(Xin, W[l], flags, xw, N);
        agg_kernel      <<<(N + 3)/4, 256, 0, stream>>>(xw, dinv, offsets, counts, csr, B[l], d_out, flags, N);
    }
    mlp_kernel<<<((N*16) + 255)/256, 256, 0, stream>>>(d_out, Wm2, bm2, flags, N);
}

// Round 2
// 503.000 us; speedup vs baseline: 1.1177x; 1.1177x over previous
//
#include <hip/hip_runtime.h>
#include <hip/hip_bf16.h>
#include <math.h>

typedef __hip_bfloat16 bf16;
typedef __attribute__((ext_vector_type(8))) short short8;
typedef __attribute__((ext_vector_type(4))) float f32x4;

__device__ __forceinline__ float elu_f(float x){ return x > 0.f ? x : expm1f(x); }
__device__ __forceinline__ float b2f(unsigned short u){ return __uint_as_float(((unsigned)u) << 16); }
__device__ __forceinline__ unsigned short f2b(float f){ bf16 h = __float2bfloat16(f); return *reinterpret_cast<unsigned short*>(&h); }

// ---------- dtype detection (parallel) ----------
__global__ __launch_bounds__(256) void detect_part_kernel(const unsigned* __restrict__ ei_u, int twoE_words,
                                                          const unsigned* __restrict__ x_u, int min_xwords,
                                                          int* __restrict__ raw){
    __shared__ int sd[256];
    __shared__ int sc[256];
    int tid = threadIdx.x;
    int gid = blockIdx.x*256 + tid;
    long long pairs = twoE_words/2;

    int orv = 0;
    if (gid < 16384 && pairs > 0){
        long long idx = ((long long)gid * pairs) / 16384;
        long long w = 2*idx + 1;
        if (w < twoE_words) orv = (int)ei_u[w];
    }
    int cnt = 0;
    int s = gid - 16384;
    if (s >= 0 && s < 4096){
        long long idx = ((long long)s * min_xwords) / 4096;
        if (idx < min_xwords){
            unsigned e = (x_u[idx] >> 7) & 0xFFu;
            cnt = (e >= 96u && e <= 160u) ? 1 : 0;
        }
    }
    sd[tid] = orv; sc[tid] = cnt;
    __syncthreads();
    #pragma unroll
    for (int off = 128; off > 0; off >>= 1){
        if (tid < off){ sd[tid] |= sd[tid+off]; sc[tid] += sc[tid+off]; }
        __syncthreads();
    }
    if (tid == 0){
        if (sd[0]) atomicOr(&raw[0], sd[0]);
        if (sc[0]) atomicAdd(&raw[1], sc[0]);
    }
}

__global__ void finalize_kernel(const int* __restrict__ raw, int* __restrict__ flags){
    flags[0] = (raw[0] == 0) ? 1 : 0;
    flags[1] = (raw[1]*2 > 4096) ? 1 : 0;
}

__device__ __forceinline__ int load_src(const int* ei, int e, int E, int is64){
    return is64 ? ei[2*e] : ei[e];
}
__device__ __forceinline__ int load_dst(const int* ei, int e, int E, int is64){
    return is64 ? ei[2*(E + e)] : ei[E + e];
}
__device__ __forceinline__ float loadf(const void* base, size_t idx, int isbf){
    return isbf ? __bfloat162float(((const bf16*)base)[idx]) : ((const float*)base)[idx];
}

// ---------- CSR build ----------
__global__ void count_kernel(const int* __restrict__ ei, const int* __restrict__ flags,
                             int* __restrict__ counts, int E, int N){
    int e = blockIdx.x*256 + threadIdx.x;
    if (e < E){
        int d = load_dst(ei, e, E, flags[0]);
        if ((unsigned)d < (unsigned)N) atomicAdd(&counts[d], 1);
    }
}

__global__ void partial_kernel(const int* __restrict__ counts, int* __restrict__ partial, int N){
    __shared__ int sd[256];
    int tid = threadIdx.x;
    int i = blockIdx.x*256 + tid;
    sd[tid] = (i < N) ? counts[i] : 0;
    __syncthreads();
    #pragma unroll
    for (int off = 128; off > 0; off >>= 1){
        if (tid < off) sd[tid] += sd[tid+off];
        __syncthreads();
    }
    if (tid == 0) partial[blockIdx.x] = sd[0];
}

__global__ void scanp_kernel(const int* __restrict__ partial, int* __restrict__ blockoff, int nb){
    __shared__ int sd[256];
    int tid = threadIdx.x;
    int v = (tid < nb) ? partial[tid] : 0;
    sd[tid] = v;
    __syncthreads();
    #pragma unroll
    for (int off = 1; off < 256; off <<= 1){
        int t = (tid >= off) ? sd[tid-off] : 0;
        __syncthreads();
        sd[tid] += t;
        __syncthreads();
    }
    if (tid < nb) blockoff[tid] = sd[tid] - v;
}

// offsets + cursor + dinv (fused)
__global__ void offsets_kernel(const int* __restrict__ counts, const int* __restrict__ blockoff,
                               int* __restrict__ offsets, int* __restrict__ cursor,
                               float* __restrict__ dinv, int N){
    __shared__ int sd[256];
    int tid = threadIdx.x;
    int i = blockIdx.x*256 + tid;
    int v = (i < N) ? counts[i] : 0;
    sd[tid] = v;
    __syncthreads();
    #pragma unroll
    for (int off = 1; off < 256; off <<= 1){
        int t = (tid >= off) ? sd[tid-off] : 0;
        __syncthreads();
        sd[tid] += t;
        __syncthreads();
    }
    if (i < N){
        int o = blockoff[blockIdx.x] + sd[tid] - v;
        offsets[i] = o;
        cursor[i]  = o;
        double d = (double)(v + 1);
        if (d < 1.0) d = 1.0;
        dinv[i] = (float)(1.0 / sqrt(d));
    }
}

__global__ void scatter_kernel(const int* __restrict__ ei, const int* __restrict__ flags,
                               int* __restrict__ cursor, int* __restrict__ csr, int E, int N){
    int e = blockIdx.x*256 + threadIdx.x;
    if (e < E){
        int is64 = flags[0];
        int d = load_dst(ei, e, E, is64);
        int s = load_src(ei, e, E, is64);
        if ((unsigned)d < (unsigned)N){
            int pos = atomicAdd(&cursor[d], 1);
            if ((unsigned)pos < (unsigned)E) csr[pos] = s;
        }
    }
}

// ---------- W prep: per layer build W^T split into bf16 hi/lo.
// WThi[l][c*128+k] = bf16(W[k][c]); WTlo = bf16(W[k][c] - hi). bf16 input: hi=raw, lo=0.
__global__ __launch_bounds__(256) void wprep_kernel(const void* __restrict__ W0, const void* __restrict__ W1,
                                                    const void* __restrict__ W2, const void* __restrict__ W3,
                                                    const int* __restrict__ flags,
                                                    unsigned short* __restrict__ WThi, unsigned short* __restrict__ WTlo){
    const void* Wl = blockIdx.x == 0 ? W0 : blockIdx.x == 1 ? W1 : blockIdx.x == 2 ? W2 : W3;
    int isbf = flags[1];
    unsigned short* dh = WThi + (size_t)blockIdx.x*16384;
    unsigned short* dl = WTlo + (size_t)blockIdx.x*16384;
    for (int i = threadIdx.x; i < 16384; i += 256){
        int k = i >> 7, c = i & 127;
        unsigned short hi, lo;
        if (isbf){
            hi = ((const unsigned short*)Wl)[i]; lo = 0;
        } else {
            float w = ((const float*)Wl)[i];
            hi = f2b(w);
            lo = f2b(w - b2f(hi));
        }
        dh[c*128 + k] = hi;
        dl[c*128 + k] = lo;
    }
}

// ---------- GEMM: Y[N,128] = X[N,128] @ W[128,128] on matrix cores.
// fp32 path: bf16x2 split (hi/lo), 3 MFMA passes, fp32-grade accuracy, fp32 out.
// bf16 path: single pass, bf16 out.
// Fragment recipe (verified m92/m97): row-major A + B^T tiles; lane reads row (lane&15),
// 8 contiguous k at 8*(lane>>4); C/D: col=lane&15, row=4*(lane>>4)+reg.
__global__ __launch_bounds__(256) void gemm_kernel(const void* __restrict__ X,
                                                   const unsigned short* __restrict__ WThi,
                                                   const unsigned short* __restrict__ WTlo,
                                                   const int* __restrict__ flags,
                                                   void* __restrict__ Y, int N){
    __shared__ __align__(16) unsigned short xhi[64*136];
    __shared__ __align__(16) unsigned short xlo[64*136];
    __shared__ __align__(16) unsigned short bh[128*40];   // per-k0 chunk: 128 rows x 32 k (+8 pad)
    __shared__ __align__(16) unsigned short bl[128*40];
    int tid = threadIdx.x;
    int r0 = blockIdx.x*64;
    int isbf = flags[1];

    if (isbf){
        for (int i = tid; i < 64*16; i += 256){
            int r = i >> 4, sg = i & 15;
            float4 v = make_float4(0.f,0.f,0.f,0.f);
            if (r0 + r < N) v = ((const float4*)X)[(size_t)(r0+r)*16 + sg];
            *(float4*)&xhi[r*136 + sg*8] = v;
        }
    } else {
        for (int i = tid; i < 64*32; i += 256){
            int r = i >> 5, f4 = i & 31;
            float4 v = make_float4(0.f,0.f,0.f,0.f);
            if (r0 + r < N) v = ((const float4*)X)[(size_t)(r0+r)*32 + f4];
            ushort4 hv, lv;
            hv.x = f2b(v.x); lv.x = f2b(v.x - b2f(hv.x));
            hv.y = f2b(v.y); lv.y = f2b(v.y - b2f(hv.y));
            hv.z = f2b(v.z); lv.z = f2b(v.z - b2f(hv.z));
            hv.w = f2b(v.w); lv.w = f2b(v.w - b2f(hv.w));
            *(ushort4*)&xhi[r*136 + f4*4] = hv;
            *(ushort4*)&xlo[r*136 + f4*4] = lv;
        }
    }

    int wv = tid >> 6, lane = tid & 63;
    int lq = lane & 15, lh = lane >> 4;

    f32x4 acc[8];
    #pragma unroll
    for (int i = 0; i < 8; i++){
        #pragma unroll
        for (int e = 0; e < 4; e++) acc[i][e] = 0.f;
    }

    for (int k0 = 0; k0 < 4; k0++){
        __syncthreads();   // protect b-chunk from previous iteration's readers; k0=0: cover x staging
        for (int i = tid; i < 512; i += 256){
            int rr = i >> 2, sg = i & 3;
            *(float4*)&bh[rr*40 + sg*8] = *(const float4*)&WThi[rr*128 + k0*32 + sg*8];
        }
        if (!isbf){
            for (int i = tid; i < 512; i += 256){
                int rr = i >> 2, sg = i & 3;
                *(float4*)&bl[rr*40 + sg*8] = *(const float4*)&WTlo[rr*128 + k0*32 + sg*8];
            }
        }
        __syncthreads();

        short8 ah = *reinterpret_cast<const short8*>(&xhi[(wv*16 + lq)*136 + k0*32 + lh*8]);
        if (isbf){
            #pragma unroll
            for (int nt = 0; nt < 8; nt++){
                short8 bhf = *reinterpret_cast<const short8*>(&bh[(nt*16 + lq)*40 + lh*8]);
                acc[nt] = __builtin_amdgcn_mfma_f32_16x16x32_bf16(ah, bhf, acc[nt], 0, 0, 0);
            }
        } else {
            short8 al = *reinterpret_cast<const short8*>(&xlo[(wv*16 + lq)*136 + k0*32 + lh*8]);
            #pragma unroll
            for (int nt = 0; nt < 8; nt++){
                short8 bhf = *reinterpret_cast<const short8*>(&bh[(nt*16 + lq)*40 + lh*8]);
                short8 blf = *reinterpret_cast<const short8*>(&bl[(nt*16 + lq)*40 + lh*8]);
                acc[nt] = __builtin_amdgcn_mfma_f32_16x16x32_bf16(ah, bhf, acc[nt], 0, 0, 0);
                acc[nt] = __builtin_amdgcn_mfma_f32_16x16x32_bf16(al, bhf, acc[nt], 0, 0, 0);
                acc[nt] = __builtin_amdgcn_mfma_f32_16x16x32_bf16(ah, blf, acc[nt], 0, 0, 0);
            }
        }
    }

    if (isbf){
        bf16* Yb = (bf16*)Y;
        #pragma unroll
        for (int nt = 0; nt < 8; nt++){
            #pragma unroll
            for (int i = 0; i < 4; i++){
                int row = r0 + wv*16 + lh*4 + i;
                if (row < N) Yb[(size_t)row*128 + nt*16 + lq] = __float2bfloat16(acc[nt][i]);
            }
        }
    } else {
        float* Yf = (float*)Y;
        #pragma unroll
        for (int nt = 0; nt < 8; nt++){
            #pragma unroll
            for (int i = 0; i < 4; i++){
                int row = r0 + wv*16 + lh*4 + i;
                if (row < N) Yf[(size_t)row*128 + nt*16 + lq] = acc[nt][i];
            }
        }
    }
}

// ---------- aggregation: one wave per dst row (traffic-floor-bound; structure kept) ----------
__global__ __launch_bounds__(256) void agg_kernel(const void* __restrict__ XW, const float* __restrict__ dinv,
                                                  const int* __restrict__ offsets, const int* __restrict__ counts,
                                                  const int* __restrict__ csr, const void* __restrict__ bias,
                                                  void* __restrict__ Hout, const int* __restrict__ flags, int N){
    int wave = threadIdx.x >> 6;
    int lane = threadIdx.x & 63;
    int n = blockIdx.x*4 + wave;
    if (n >= N) return;
    int isbf = flags[1];

    float dn = dinv[n];
    float sw = dn*dn;

    if (isbf){
        int h = lane >> 5, q = lane & 31;
        const ushort4* X4 = (const ushort4*)XW;
        float a0, a1, a2, a3;
        if (h == 0){
            ushort4 v = X4[(size_t)n*32 + q];
            a0 = b2f(v.x)*sw; a1 = b2f(v.y)*sw; a2 = b2f(v.z)*sw; a3 = b2f(v.w)*sw;
        } else { a0 = a1 = a2 = a3 = 0.f; }

        int j0 = offsets[n], cnt = counts[n];
        for (int base = 0; base < cnt; base += 64){
            int m = cnt - base; if (m > 64) m = 64;
            int s_l = 0; float w_l = 0.f;
            if (lane < m){
                int s = csr[j0 + base + lane];
                if ((unsigned)s < (unsigned)N){ s_l = s; w_l = dinv[s]*dn; }
            }
            int j = 0;
            for (; j + 8 <= m; j += 8){
                int   s0 = __shfl(s_l, j + h),     s1 = __shfl(s_l, j + 2 + h);
                int   s2 = __shfl(s_l, j + 4 + h), s3 = __shfl(s_l, j + 6 + h);
                float w0 = __shfl(w_l, j + h),     w1 = __shfl(w_l, j + 2 + h);
                float w2 = __shfl(w_l, j + 4 + h), w3 = __shfl(w_l, j + 6 + h);
                ushort4 u0 = X4[(size_t)s0*32 + q];
                ushort4 u1 = X4[(size_t)s1*32 + q];
                ushort4 u2 = X4[(size_t)s2*32 + q];
                ushort4 u3 = X4[(size_t)s3*32 + q];
                a0 += b2f(u0.x)*w0; a1 += b2f(u0.y)*w0; a2 += b2f(u0.z)*w0; a3 += b2f(u0.w)*w0;
                a0 += b2f(u1.x)*w1; a1 += b2f(u1.y)*w1; a2 += b2f(u1.z)*w1; a3 += b2f(u1.w)*w1;
                a0 += b2f(u2.x)*w2; a1 += b2f(u2.y)*w2; a2 += b2f(u2.z)*w2; a3 += b2f(u2.w)*w2;
                a0 += b2f(u3.x)*w3; a1 += b2f(u3.y)*w3; a2 += b2f(u3.z)*w3; a3 += b2f(u3.w)*w3;
            }
            for (; j < m; j += 2){
                int   s = __shfl(s_l, j + h);
                float w = __shfl(w_l, j + h);
                ushort4 u = X4[(size_t)s*32 + q];
                a0 += b2f(u.x)*w; a1 += b2f(u.y)*w; a2 += b2f(u.z)*w; a3 += b2f(u.w)*w;
            }
        }
        a0 += __shfl_xor(a0, 32);
        a1 += __shfl_xor(a1, 32);
        a2 += __shfl_xor(a2, 32);
        a3 += __shfl_xor(a3, 32);
        if (h == 0){
            a0 = elu_f(a0 + loadf(bias, 4*q + 0, 1));
            a1 = elu_f(a1 + loadf(bias, 4*q + 1, 1));
            a2 = elu_f(a2 + loadf(bias, 4*q + 2, 1));
            a3 = elu_f(a3 + loadf(bias, 4*q + 3, 1));
            ushort4 o;
            o.x = f2b(a0); o.y = f2b(a1); o.z = f2b(a2); o.w = f2b(a3);
            ((ushort4*)Hout)[(size_t)n*32 + q] = o;
        }
    } else {
        float accx, accy;
        float2 v = ((const float2*)XW)[(size_t)n*64 + lane];
        accx = v.x*sw; accy = v.y*sw;

        int j0 = offsets[n], cnt = counts[n];
        for (int base = 0; base < cnt; base += 64){
            int m = cnt - base; if (m > 64) m = 64;
            int s_l = 0; float w_l = 0.f;
            if (lane < m){
                int s = csr[j0 + base + lane];
                if ((unsigned)s < (unsigned)N){ s_l = s; w_l = dinv[s]*dn; }
            }
            int j = 0;
            const float2* XF = (const float2*)XW;
            for (; j + 4 <= m; j += 4){
                int   s0 = __shfl(s_l, j),   s1 = __shfl(s_l, j+1), s2 = __shfl(s_l, j+2), s3 = __shfl(s_l, j+3);
                float w0 = __shfl(w_l, j),   w1 = __shfl(w_l, j+1), w2 = __shfl(w_l, j+2), w3 = __shfl(w_l, j+3);
                float2 u0 = XF[(size_t)s0*64 + lane];
                float2 u1 = XF[(size_t)s1*64 + lane];
                float2 u2 = XF[(size_t)s2*64 + lane];
                float2 u3 = XF[(size_t)s3*64 + lane];
                accx += u0.x*w0; accy += u0.y*w0;
                accx += u1.x*w1; accy += u1.y*w1;
                accx += u2.x*w2; accy += u2.y*w2;
                accx += u3.x*w3; accy += u3.y*w3;
            }
            for (; j < m; ++j){
                int   s = __shfl(s_l, j);
                float w = __shfl(w_l, j);
                float2 u = XF[(size_t)s*64 + lane];
                accx += u.x*w; accy += u.y*w;
            }
        }

        accx = elu_f(accx + loadf(bias, lane*2,     0));
        accy = elu_f(accy + loadf(bias, lane*2 + 1, 0));
        *(float2*)((float*)Hout + (size_t)n*128 + lane*2) = make_float2(accx, accy);
    }
}

// ---------- MLP head (only Wm2/bm2 survive the reference's reassignment bug) ----------
__global__ __launch_bounds__(256) void mlp_kernel(void* __restrict__ dout, const void* __restrict__ Wm,
                                                  const void* __restrict__ bm, const int* __restrict__ flags, int N){
    __shared__ float ws_[1280];
    __shared__ __align__(16) float hs[16][136];
    int tid = threadIdx.x;
    int isbf = flags[1];
    for (int i = tid; i < 1280; i += 256) ws_[i] = loadf(Wm, i, isbf);

    int r = tid >> 4, c = tid & 15;
    int row = blockIdx.x*16 + r;
    if (isbf){
        if (row < N){
            float4 v = ((const float4*)dout)[(size_t)row*16 + c];   // 8 bf16
            const unsigned short* u = (const unsigned short*)&v;
            #pragma unroll
            for (int j = 0; j < 8; j++) hs[r][c*8 + j] = b2f(u[j]);
        }
    } else {
        if (row < N){
            float4 v0 = ((const float4*)dout)[(size_t)row*32 + c*2];
            float4 v1 = ((const float4*)dout)[(size_t)row*32 + c*2 + 1];
            *(float4*)&hs[r][c*8]     = v0;
            *(float4*)&hs[r][c*8 + 4] = v1;
        }
    }
    __syncthreads();
    if (row < N && c < 10){
        float acc = 0.f;
        #pragma unroll 8
        for (int k = 0; k < 128; k++) acc += hs[r][k]*ws_[k*10 + c];
        acc += loadf(bm, c, isbf);
        float res = elu_f(acc);
        if (isbf){
            ((bf16*)dout)[(size_t)N*128 + (size_t)row*10 + c] = __float2bfloat16(res);
        } else {
            ((float*)dout)[(size_t)N*128 + (size_t)row*10 + c] = res;
        }
    }
}

static inline char* alignup(char* p, size_t a){ return (char*)(((uintptr_t)p + a - 1) & ~(a - 1)); }

extern "C" void kernel_launch(void* const* d_in, const int* in_sizes, int n_in,
                              void* d_out, int out_size, void* d_ws, size_t ws_size,
                              hipStream_t stream){
    const void* x  = d_in[0];
    const int*  ei = (const int*)d_in[1];
    const void* W[4] = {d_in[2], d_in[4], d_in[6], d_in[8]};
    const void* B[4] = {d_in[3], d_in[5], d_in[7], d_in[9]};
    const void* Wm2 = d_in[12];
    const void* bm2 = d_in[13];

    int N = in_sizes[0] / 128;
    int E = in_sizes[1] / 2;

    char* p = (char*)d_ws;
    int*   flags    = (int*)p;
    int*   raw      = flags + 2;                   p = alignup(p + 4*sizeof(int), 256);
    float* dinv     = (float*)p;                   p = alignup(p + (size_t)N*4, 256);
    int*   counts   = (int*)p;                     p = alignup(p + (size_t)N*4, 256);
    int*   offsets  = (int*)p;                     p = alignup(p + (size_t)N*4, 256);
    int*   cursor   = (int*)p;                     p = alignup(p + (size_t)N*4, 256);
    int*   partial  = (int*)p;                     p = alignup(p + 256*4, 256);
    int*   blockoff = (int*)p;                     p = alignup(p + 256*4, 256);
    int*   csr      = (int*)p;                     p = alignup(p + (size_t)E*4, 256);
    void*  xw       = (void*)p;                    p = alignup(p + (size_t)N*128*4, 256);
    unsigned short* WThi = (unsigned short*)p;     p = alignup(p + (size_t)4*16384*2, 256);
    unsigned short* WTlo = (unsigned short*)p;     p = alignup(p + (size_t)4*16384*2, 256);

    int nb = (N + 255)/256;   // 196 <= 256: single-block top scan valid

    hipMemsetAsync(flags, 0, 4*sizeof(int), stream);
    hipMemsetAsync(counts, 0, (size_t)N*sizeof(int), stream);
    detect_part_kernel<<<128, 256, 0, stream>>>((const unsigned*)ei, 2*E, (const unsigned*)x, N*128/2, raw);
    finalize_kernel   <<<1, 1, 0, stream>>>(raw, flags);
    wprep_kernel  <<<4, 256, 0, stream>>>(W[0], W[1], W[2], W[3], flags, WThi, WTlo);
    count_kernel  <<<(E + 255)/256, 256, 0, stream>>>(ei, flags, counts, E, N);
    partial_kernel<<<nb, 256, 0, stream>>>(counts, partial, N);
    scanp_kernel  <<<1, 256, 0, stream>>>(partial, blockoff, nb);
    offsets_kernel<<<nb, 256, 0, stream>>>(counts, blockoff, offsets, cursor, dinv, N);
    scatter_kernel<<<(E + 255)/256, 256, 0, stream>>>(ei, flags, cursor, csr, E, N);

    for (int l = 0; l < 4; ++l){
        const void* Xin = (l == 0) ? x : (const void*)d_out;
        gemm_kernel<<<(N + 63)/64, 256, 0, stream>>>(Xin, WThi + (size_t)l*16384, WTlo + (size_t)l*16384, flags, xw, N);
        agg_kernel <<<(N + 3)/4, 256, 0, stream>>>(xw, dinv, offsets, counts, csr, B[l], d_out, flags, N);
    }
    mlp_kernel<<<((N*16) + 255)/256, 256, 0, stream>>>(d_out, Wm2, bm2, flags, N);
}

// Round 3
// 487.213 us; speedup vs baseline: 1.1539x; 1.0324x over previous
//
#include <hip/hip_runtime.h>
#include <hip/hip_bf16.h>
#include <math.h>

typedef __hip_bfloat16 bf16;
typedef __attribute__((ext_vector_type(8))) short short8;
typedef __attribute__((ext_vector_type(4))) float f32x4;

__device__ __forceinline__ float elu_f(float x){ return x > 0.f ? x : expm1f(x); }
__device__ __forceinline__ float b2f(unsigned short u){ return __uint_as_float(((unsigned)u) << 16); }
__device__ __forceinline__ unsigned short f2b(float f){ bf16 h = __float2bfloat16(f); return *reinterpret_cast<unsigned short*>(&h); }

// ---------- dtype detection (parallel) ----------
__global__ __launch_bounds__(256) void detect_part_kernel(const unsigned* __restrict__ ei_u, int twoE_words,
                                                          const unsigned* __restrict__ x_u, int min_xwords,
                                                          int* __restrict__ raw){
    __shared__ int sd[256];
    __shared__ int sc[256];
    int tid = threadIdx.x;
    int gid = blockIdx.x*256 + tid;
    long long pairs = twoE_words/2;

    int orv = 0;
    if (gid < 16384 && pairs > 0){
        long long idx = ((long long)gid * pairs) / 16384;
        long long w = 2*idx + 1;
        if (w < twoE_words) orv = (int)ei_u[w];
    }
    int cnt = 0;
    int s = gid - 16384;
    if (s >= 0 && s < 4096){
        long long idx = ((long long)s * min_xwords) / 4096;
        if (idx < min_xwords){
            unsigned e = (x_u[idx] >> 7) & 0xFFu;
            cnt = (e >= 96u && e <= 160u) ? 1 : 0;
        }
    }
    sd[tid] = orv; sc[tid] = cnt;
    __syncthreads();
    #pragma unroll
    for (int off = 128; off > 0; off >>= 1){
        if (tid < off){ sd[tid] |= sd[tid+off]; sc[tid] += sc[tid+off]; }
        __syncthreads();
    }
    if (tid == 0){
        if (sd[0]) atomicOr(&raw[0], sd[0]);
        if (sc[0]) atomicAdd(&raw[1], sc[0]);
    }
}

__global__ void finalize_kernel(const int* __restrict__ raw, int* __restrict__ flags){
    flags[0] = (raw[0] == 0) ? 1 : 0;
    flags[1] = (raw[1]*2 > 4096) ? 1 : 0;
}

__device__ __forceinline__ int load_src(const int* ei, int e, int E, int is64){
    return is64 ? ei[2*e] : ei[e];
}
__device__ __forceinline__ int load_dst(const int* ei, int e, int E, int is64){
    return is64 ? ei[2*(E + e)] : ei[E + e];
}
__device__ __forceinline__ float loadf(const void* base, size_t idx, int isbf){
    return isbf ? __bfloat162float(((const bf16*)base)[idx]) : ((const float*)base)[idx];
}

// ---------- CSR build ----------
__global__ void count_kernel(const int* __restrict__ ei, const int* __restrict__ flags,
                             int* __restrict__ counts, int E, int N){
    int e = blockIdx.x*256 + threadIdx.x;
    if (e < E){
        int d = load_dst(ei, e, E, flags[0]);
        if ((unsigned)d < (unsigned)N) atomicAdd(&counts[d], 1);
    }
}

__global__ void partial_kernel(const int* __restrict__ counts, int* __restrict__ partial, int N){
    __shared__ int sd[256];
    int tid = threadIdx.x;
    int i = blockIdx.x*256 + tid;
    sd[tid] = (i < N) ? counts[i] : 0;
    __syncthreads();
    #pragma unroll
    for (int off = 128; off > 0; off >>= 1){
        if (tid < off) sd[tid] += sd[tid+off];
        __syncthreads();
    }
    if (tid == 0) partial[blockIdx.x] = sd[0];
}

__global__ void scanp_kernel(const int* __restrict__ partial, int* __restrict__ blockoff, int nb){
    __shared__ int sd[256];
    int tid = threadIdx.x;
    int v = (tid < nb) ? partial[tid] : 0;
    sd[tid] = v;
    __syncthreads();
    #pragma unroll
    for (int off = 1; off < 256; off <<= 1){
        int t = (tid >= off) ? sd[tid-off] : 0;
        __syncthreads();
        sd[tid] += t;
        __syncthreads();
    }
    if (tid < nb) blockoff[tid] = sd[tid] - v;
}

// offsets + cursor + dinv (fused)
__global__ void offsets_kernel(const int* __restrict__ counts, const int* __restrict__ blockoff,
                               int* __restrict__ offsets, int* __restrict__ cursor,
                               float* __restrict__ dinv, int N){
    __shared__ int sd[256];
    int tid = threadIdx.x;
    int i = blockIdx.x*256 + tid;
    int v = (i < N) ? counts[i] : 0;
    sd[tid] = v;
    __syncthreads();
    #pragma unroll
    for (int off = 1; off < 256; off <<= 1){
        int t = (tid >= off) ? sd[tid-off] : 0;
        __syncthreads();
        sd[tid] += t;
        __syncthreads();
    }
    if (i < N){
        int o = blockoff[blockIdx.x] + sd[tid] - v;
        offsets[i] = o;
        cursor[i]  = o;
        double d = (double)(v + 1);
        if (d < 1.0) d = 1.0;
        dinv[i] = (float)(1.0 / sqrt(d));
    }
}

__global__ void scatter_kernel(const int* __restrict__ ei, const int* __restrict__ flags,
                               int* __restrict__ cursor, int* __restrict__ csr, int E, int N){
    int e = blockIdx.x*256 + threadIdx.x;
    if (e < E){
        int is64 = flags[0];
        int d = load_dst(ei, e, E, is64);
        int s = load_src(ei, e, E, is64);
        if ((unsigned)d < (unsigned)N){
            int pos = atomicAdd(&cursor[d], 1);
            if ((unsigned)pos < (unsigned)E) csr[pos] = s;
        }
    }
}

// ---------- W prep: W^T split into bf16 hi/lo. 256 blocks (64/layer); thread = one output
// element -> coalesced stores; gather reads hit L2 (64KB/W). ----------
__global__ __launch_bounds__(256) void wprep_kernel(const void* __restrict__ W0, const void* __restrict__ W1,
                                                    const void* __restrict__ W2, const void* __restrict__ W3,
                                                    const int* __restrict__ flags,
                                                    unsigned short* __restrict__ WThi, unsigned short* __restrict__ WTlo){
    int l = blockIdx.x >> 6;
    const void* Wl = l == 0 ? W0 : l == 1 ? W1 : l == 2 ? W2 : W3;
    int isbf = flags[1];
    int o = (blockIdx.x & 63)*256 + threadIdx.x;   // o = c*128 + k
    int c = o >> 7, k = o & 127;
    unsigned short hi, lo;
    if (isbf){
        hi = ((const unsigned short*)Wl)[k*128 + c]; lo = 0;
    } else {
        float w = ((const float*)Wl)[k*128 + c];
        hi = f2b(w);
        lo = f2b(w - b2f(hi));
    }
    WThi[(size_t)l*16384 + o] = hi;
    WTlo[(size_t)l*16384 + o] = lo;
}

// ---------- GEMM: Y[N,128] = X[N,128] @ W[128,128] on matrix cores.
// fp32 path: bf16x2 split (hi/lo), 3 MFMA passes, fp32-grade accuracy, fp32 out.
// bf16 path: single pass, bf16 out.
// Fragment recipe (verified m92/m97): row-major A + B^T tiles; lane reads row (lane&15),
// 8 contiguous k at 8*(lane>>4); C/D: col=lane&15, row=4*(lane>>4)+reg.
__global__ __launch_bounds__(256) void gemm_kernel(const void* __restrict__ X,
                                                   const unsigned short* __restrict__ WThi,
                                                   const unsigned short* __restrict__ WTlo,
                                                   const int* __restrict__ flags,
                                                   void* __restrict__ Y, int N){
    __shared__ __align__(16) unsigned short xhi[64*136];
    __shared__ __align__(16) unsigned short xlo[64*136];
    __shared__ __align__(16) unsigned short bh[128*40];   // per-k0 chunk: 128 rows x 32 k (+8 pad)
    __shared__ __align__(16) unsigned short bl[128*40];
    int tid = threadIdx.x;
    int r0 = blockIdx.x*64;
    int isbf = flags[1];

    if (isbf){
        for (int i = tid; i < 64*16; i += 256){
            int r = i >> 4, sg = i & 15;
            float4 v = make_float4(0.f,0.f,0.f,0.f);
            if (r0 + r < N) v = ((const float4*)X)[(size_t)(r0+r)*16 + sg];
            *(float4*)&xhi[r*136 + sg*8] = v;
        }
    } else {
        for (int i = tid; i < 64*32; i += 256){
            int r = i >> 5, f4 = i & 31;
            float4 v = make_float4(0.f,0.f,0.f,0.f);
            if (r0 + r < N) v = ((const float4*)X)[(size_t)(r0+r)*32 + f4];
            ushort4 hv, lv;
            hv.x = f2b(v.x); lv.x = f2b(v.x - b2f(hv.x));
            hv.y = f2b(v.y); lv.y = f2b(v.y - b2f(hv.y));
            hv.z = f2b(v.z); lv.z = f2b(v.z - b2f(hv.z));
            hv.w = f2b(v.w); lv.w = f2b(v.w - b2f(hv.w));
            *(ushort4*)&xhi[r*136 + f4*4] = hv;
            *(ushort4*)&xlo[r*136 + f4*4] = lv;
        }
    }

    int wv = tid >> 6, lane = tid & 63;
    int lq = lane & 15, lh = lane >> 4;

    f32x4 acc[8];
    #pragma unroll
    for (int i = 0; i < 8; i++){
        #pragma unroll
        for (int e = 0; e < 4; e++) acc[i][e] = 0.f;
    }

    for (int k0 = 0; k0 < 4; k0++){
        __syncthreads();   // protect b-chunk from previous iteration's readers; k0=0: cover x staging
        for (int i = tid; i < 512; i += 256){
            int rr = i >> 2, sg = i & 3;
            *(float4*)&bh[rr*40 + sg*8] = *(const float4*)&WThi[rr*128 + k0*32 + sg*8];
        }
        if (!isbf){
            for (int i = tid; i < 512; i += 256){
                int rr = i >> 2, sg = i & 3;
                *(float4*)&bl[rr*40 + sg*8] = *(const float4*)&WTlo[rr*128 + k0*32 + sg*8];
            }
        }
        __syncthreads();

        short8 ah = *reinterpret_cast<const short8*>(&xhi[(wv*16 + lq)*136 + k0*32 + lh*8]);
        if (isbf){
            #pragma unroll
            for (int nt = 0; nt < 8; nt++){
                short8 bhf = *reinterpret_cast<const short8*>(&bh[(nt*16 + lq)*40 + lh*8]);
                acc[nt] = __builtin_amdgcn_mfma_f32_16x16x32_bf16(ah, bhf, acc[nt], 0, 0, 0);
            }
        } else {
            short8 al = *reinterpret_cast<const short8*>(&xlo[(wv*16 + lq)*136 + k0*32 + lh*8]);
            #pragma unroll
            for (int nt = 0; nt < 8; nt++){
                short8 bhf = *reinterpret_cast<const short8*>(&bh[(nt*16 + lq)*40 + lh*8]);
                short8 blf = *reinterpret_cast<const short8*>(&bl[(nt*16 + lq)*40 + lh*8]);
                acc[nt] = __builtin_amdgcn_mfma_f32_16x16x32_bf16(ah, bhf, acc[nt], 0, 0, 0);
                acc[nt] = __builtin_amdgcn_mfma_f32_16x16x32_bf16(al, bhf, acc[nt], 0, 0, 0);
                acc[nt] = __builtin_amdgcn_mfma_f32_16x16x32_bf16(ah, blf, acc[nt], 0, 0, 0);
            }
        }
    }

    if (isbf){
        bf16* Yb = (bf16*)Y;
        #pragma unroll
        for (int nt = 0; nt < 8; nt++){
            #pragma unroll
            for (int i = 0; i < 4; i++){
                int row = r0 + wv*16 + lh*4 + i;
                if (row < N) Yb[(size_t)row*128 + nt*16 + lq] = __float2bfloat16(acc[nt][i]);
            }
        }
    } else {
        float* Yf = (float*)Y;
        #pragma unroll
        for (int nt = 0; nt < 8; nt++){
            #pragma unroll
            for (int i = 0; i < 4; i++){
                int row = r0 + wv*16 + lh*4 + i;
                if (row < N) Yf[(size_t)row*128 + nt*16 + lq] = acc[nt][i];
            }
        }
    }
}

// ---------- aggregation: one wave per dst row. Both dtypes: 16B/lane, half-wave pairs ->
// 2 neighbor rows per VMEM instr, 8 edges (2KB/wave) in flight per unrolled group. ----------
__global__ __launch_bounds__(256) void agg_kernel(const void* __restrict__ XW, const float* __restrict__ dinv,
                                                  const int* __restrict__ offsets, const int* __restrict__ counts,
                                                  const int* __restrict__ csr, const void* __restrict__ bias,
                                                  void* __restrict__ Hout, const int* __restrict__ flags, int N){
    int wave = threadIdx.x >> 6;
    int lane = threadIdx.x & 63;
    int n = blockIdx.x*4 + wave;
    if (n >= N) return;
    int isbf = flags[1];

    float dn = dinv[n];
    float sw = dn*dn;

    if (isbf){
        int h = lane >> 5, q = lane & 31;
        const ushort4* X4 = (const ushort4*)XW;
        float a0, a1, a2, a3;
        if (h == 0){
            ushort4 v = X4[(size_t)n*32 + q];
            a0 = b2f(v.x)*sw; a1 = b2f(v.y)*sw; a2 = b2f(v.z)*sw; a3 = b2f(v.w)*sw;
        } else { a0 = a1 = a2 = a3 = 0.f; }

        int j0 = offsets[n], cnt = counts[n];
        for (int base = 0; base < cnt; base += 64){
            int m = cnt - base; if (m > 64) m = 64;
            int s_l = 0; float w_l = 0.f;
            if (lane < m){
                int s = csr[j0 + base + lane];
                if ((unsigned)s < (unsigned)N){ s_l = s; w_l = dinv[s]*dn; }
            }
            int j = 0;
            for (; j + 8 <= m; j += 8){
                int   s0 = __shfl(s_l, j + h),     s1 = __shfl(s_l, j + 2 + h);
                int   s2 = __shfl(s_l, j + 4 + h), s3 = __shfl(s_l, j + 6 + h);
                float w0 = __shfl(w_l, j + h),     w1 = __shfl(w_l, j + 2 + h);
                float w2 = __shfl(w_l, j + 4 + h), w3 = __shfl(w_l, j + 6 + h);
                ushort4 u0 = X4[(size_t)s0*32 + q];
                ushort4 u1 = X4[(size_t)s1*32 + q];
                ushort4 u2 = X4[(size_t)s2*32 + q];
                ushort4 u3 = X4[(size_t)s3*32 + q];
                a0 += b2f(u0.x)*w0; a1 += b2f(u0.y)*w0; a2 += b2f(u0.z)*w0; a3 += b2f(u0.w)*w0;
                a0 += b2f(u1.x)*w1; a1 += b2f(u1.y)*w1; a2 += b2f(u1.z)*w1; a3 += b2f(u1.w)*w1;
                a0 += b2f(u2.x)*w2; a1 += b2f(u2.y)*w2; a2 += b2f(u2.z)*w2; a3 += b2f(u2.w)*w2;
                a0 += b2f(u3.x)*w3; a1 += b2f(u3.y)*w3; a2 += b2f(u3.z)*w3; a3 += b2f(u3.w)*w3;
            }
            for (; j < m; j += 2){
                int   s = __shfl(s_l, j + h);
                float w = __shfl(w_l, j + h);
                ushort4 u = X4[(size_t)s*32 + q];
                a0 += b2f(u.x)*w; a1 += b2f(u.y)*w; a2 += b2f(u.z)*w; a3 += b2f(u.w)*w;
            }
        }
        a0 += __shfl_xor(a0, 32);
        a1 += __shfl_xor(a1, 32);
        a2 += __shfl_xor(a2, 32);
        a3 += __shfl_xor(a3, 32);
        if (h == 0){
            a0 = elu_f(a0 + loadf(bias, 4*q + 0, 1));
            a1 = elu_f(a1 + loadf(bias, 4*q + 1, 1));
            a2 = elu_f(a2 + loadf(bias, 4*q + 2, 1));
            a3 = elu_f(a3 + loadf(bias, 4*q + 3, 1));
            ushort4 o;
            o.x = f2b(a0); o.y = f2b(a1); o.z = f2b(a2); o.w = f2b(a3);
            ((ushort4*)Hout)[(size_t)n*32 + q] = o;
        }
    } else {
        int h = lane >> 5, q = lane & 31;   // lane covers features 4q..4q+3; halves split edges
        const float4* X4 = (const float4*)XW;
        float a0, a1, a2, a3;
        if (h == 0){
            float4 v = X4[(size_t)n*32 + q];
            a0 = v.x*sw; a1 = v.y*sw; a2 = v.z*sw; a3 = v.w*sw;
        } else { a0 = a1 = a2 = a3 = 0.f; }

        int j0 = offsets[n], cnt = counts[n];
        for (int base = 0; base < cnt; base += 64){
            int m = cnt - base; if (m > 64) m = 64;
            int s_l = 0; float w_l = 0.f;
            if (lane < m){
                int s = csr[j0 + base + lane];
                if ((unsigned)s < (unsigned)N){ s_l = s; w_l = dinv[s]*dn; }
            }
            int j = 0;
            for (; j + 8 <= m; j += 8){
                int   s0 = __shfl(s_l, j + h),     s1 = __shfl(s_l, j + 2 + h);
                int   s2 = __shfl(s_l, j + 4 + h), s3 = __shfl(s_l, j + 6 + h);
                float w0 = __shfl(w_l, j + h),     w1 = __shfl(w_l, j + 2 + h);
                float w2 = __shfl(w_l, j + 4 + h), w3 = __shfl(w_l, j + 6 + h);
                float4 u0 = X4[(size_t)s0*32 + q];
                float4 u1 = X4[(size_t)s1*32 + q];
                float4 u2 = X4[(size_t)s2*32 + q];
                float4 u3 = X4[(size_t)s3*32 + q];
                a0 += u0.x*w0; a1 += u0.y*w0; a2 += u0.z*w0; a3 += u0.w*w0;
                a0 += u1.x*w1; a1 += u1.y*w1; a2 += u1.z*w1; a3 += u1.w*w1;
                a0 += u2.x*w2; a1 += u2.y*w2; a2 += u2.z*w2; a3 += u2.w*w2;
                a0 += u3.x*w3; a1 += u3.y*w3; a2 += u3.z*w3; a3 += u3.w*w3;
            }
            for (; j < m; j += 2){
                // odd tail: half 1 reads lane index == m, whose prefetch is (0, 0.f) -> contributes 0
                int   s = __shfl(s_l, j + h);
                float w = __shfl(w_l, j + h);
                float4 u = X4[(size_t)s*32 + q];
                a0 += u.x*w; a1 += u.y*w; a2 += u.z*w; a3 += u.w*w;
            }
        }
        a0 += __shfl_xor(a0, 32);
        a1 += __shfl_xor(a1, 32);
        a2 += __shfl_xor(a2, 32);
        a3 += __shfl_xor(a3, 32);
        if (h == 0){
            a0 = elu_f(a0 + ((const float*)bias)[4*q + 0]);
            a1 = elu_f(a1 + ((const float*)bias)[4*q + 1]);
            a2 = elu_f(a2 + ((const float*)bias)[4*q + 2]);
            a3 = elu_f(a3 + ((const float*)bias)[4*q + 3]);
            ((float4*)Hout)[(size_t)n*32 + q] = make_float4(a0, a1, a2, a3);
        }
    }
}

// ---------- MLP head (only Wm2/bm2 survive the reference's reassignment bug) ----------
__global__ __launch_bounds__(256) void mlp_kernel(void* __restrict__ dout, const void* __restrict__ Wm,
                                                  const void* __restrict__ bm, const int* __restrict__ flags, int N){
    __shared__ float ws_[1280];
    __shared__ __align__(16) float hs[16][136];
    int tid = threadIdx.x;
    int isbf = flags[1];
    for (int i = tid; i < 1280; i += 256) ws_[i] = loadf(Wm, i, isbf);

    int r = tid >> 4, c = tid & 15;
    int row = blockIdx.x*16 + r;
    if (isbf){
        if (row < N){
            float4 v = ((const float4*)dout)[(size_t)row*16 + c];   // 8 bf16
            const unsigned short* u = (const unsigned short*)&v;
            #pragma unroll
            for (int j = 0; j < 8; j++) hs[r][c*8 + j] = b2f(u[j]);
        }
    } else {
        if (row < N){
            float4 v0 = ((const float4*)dout)[(size_t)row*32 + c*2];
            float4 v1 = ((const float4*)dout)[(size_t)row*32 + c*2 + 1];
            *(float4*)&hs[r][c*8]     = v0;
            *(float4*)&hs[r][c*8 + 4] = v1;
        }
    }
    __syncthreads();
    if (row < N && c < 10){
        float acc = 0.f;
        #pragma unroll 8
        for (int k = 0; k < 128; k++) acc += hs[r][k]*ws_[k*10 + c];
        acc += loadf(bm, c, isbf);
        float res = elu_f(acc);
        if (isbf){
            ((bf16*)dout)[(size_t)N*128 + (size_t)row*10 + c] = __float2bfloat16(res);
        } else {
            ((float*)dout)[(size_t)N*128 + (size_t)row*10 + c] = res;
        }
    }
}

static inline char* alignup(char* p, size_t a){ return (char*)(((uintptr_t)p + a - 1) & ~(a - 1)); }

extern "C" void kernel_launch(void* const* d_in, const int* in_sizes, int n_in,
                              void* d_out, int out_size, void* d_ws, size_t ws_size,
                              hipStream_t stream){
    const void* x  = d_in[0];
    const int*  ei = (const int*)d_in[1];
    const void* W[4] = {d_in[2], d_in[4], d_in[6], d_in[8]};
    const void* B[4] = {d_in[3], d_in[5], d_in[7], d_in[9]};
    const void* Wm2 = d_in[12];
    const void* bm2 = d_in[13];

    int N = in_sizes[0] / 128;
    int E = in_sizes[1] / 2;

    char* p = (char*)d_ws;
    int*   flags    = (int*)p;
    int*   raw      = flags + 2;                   p = alignup(p + 4*sizeof(int), 256);
    float* dinv     = (float*)p;                   p = alignup(p + (size_t)N*4, 256);
    int*   counts   = (int*)p;                     p = alignup(p + (size_t)N*4, 256);
    int*   offsets  = (int*)p;                     p = alignup(p + (size_t)N*4, 256);
    int*   cursor   = (int*)p;                     p = alignup(p + (size_t)N*4, 256);
    int*   partial  = (int*)p;                     p = alignup(p + 256*4, 256);
    int*   blockoff = (int*)p;                     p = alignup(p + 256*4, 256);
    int*   csr      = (int*)p;                     p = alignup(p + (size_t)E*4, 256);
    void*  xw       = (void*)p;                    p = alignup(p + (size_t)N*128*4, 256);
    unsigned short* WThi = (unsigned short*)p;     p = alignup(p + (size_t)4*16384*2, 256);
    unsigned short* WTlo = (unsigned short*)p;     p = alignup(p + (size_t)4*16384*2, 256);

    int nb = (N + 255)/256;   // 196 <= 256: single-block top scan valid

    hipMemsetAsync(flags, 0, 4*sizeof(int), stream);
    hipMemsetAsync(counts, 0, (size_t)N*sizeof(int), stream);
    detect_part_kernel<<<128, 256, 0, stream>>>((const unsigned*)ei, 2*E, (const unsigned*)x, N*128/2, raw);
    finalize_kernel   <<<1, 1, 0, stream>>>(raw, flags);
    wprep_kernel  <<<256, 256, 0, stream>>>(W[0], W[1], W[2], W[3], flags, WThi, WTlo);
    count_kernel  <<<(E + 255)/256, 256, 0, stream>>>(ei, flags, counts, E, N);
    partial_kernel<<<nb, 256, 0, stream>>>(counts, partial, N);
    scanp_kernel  <<<1, 256, 0, stream>>>(partial, blockoff, nb);
    offsets_kernel<<<nb, 256, 0, stream>>>(counts, blockoff, offsets, cursor, dinv, N);
    scatter_kernel<<<(E + 255)/256, 256, 0, stream>>>(ei, flags, cursor, csr, E, N);

    for (int l = 0; l < 4; ++l){
        const void* Xin = (l == 0) ? x : (const void*)d_out;
        gemm_kernel<<<(N + 63)/64, 256, 0, stream>>>(Xin, WThi + (size_t)l*16384, WTlo + (size_t)l*16384, flags, xw, N);
        agg_kernel <<<(N + 3)/4, 256, 0, stream>>>(xw, dinv, offsets, counts, csr, B[l], d_out, flags, N);
    }
    mlp_kernel<<<((N*16) + 255)/256, 256, 0, stream>>>(d_out, Wm2, bm2, flags, N);
}

// Round 4
// 409.201 us; speedup vs baseline: 1.3739x; 1.1906x over previous
//
#include <hip/hip_runtime.h>
#include <hip/hip_bf16.h>
#include <hip/hip_fp16.h>
#include <math.h>

typedef __hip_bfloat16 bf16;
typedef __attribute__((ext_vector_type(8))) short short8;
typedef __attribute__((ext_vector_type(4))) float f32x4;

__device__ __forceinline__ float elu_f(float x){ return x > 0.f ? x : expm1f(x); }
__device__ __forceinline__ float b2f(unsigned short u){ return __uint_as_float(((unsigned)u) << 16); }
__device__ __forceinline__ unsigned short f2b(float f){ bf16 h = __float2bfloat16(f); return *reinterpret_cast<unsigned short*>(&h); }
__device__ __forceinline__ float2 h2f2(unsigned u){
    __half2 h = *reinterpret_cast<__half2*>(&u);
    return make_float2(__low2float(h), __high2float(h));
}

// ---------- dtype detection (parallel) ----------
__global__ __launch_bounds__(256) void detect_part_kernel(const unsigned* __restrict__ ei_u, int twoE_words,
                                                          const unsigned* __restrict__ x_u, int min_xwords,
                                                          int* __restrict__ raw){
    __shared__ int sd[256];
    __shared__ int sc[256];
    int tid = threadIdx.x;
    int gid = blockIdx.x*256 + tid;
    long long pairs = twoE_words/2;

    int orv = 0;
    if (gid < 16384 && pairs > 0){
        long long idx = ((long long)gid * pairs) / 16384;
        long long w = 2*idx + 1;
        if (w < twoE_words) orv = (int)ei_u[w];
    }
    int cnt = 0;
    int s = gid - 16384;
    if (s >= 0 && s < 4096){
        long long idx = ((long long)s * min_xwords) / 4096;
        if (idx < min_xwords){
            unsigned e = (x_u[idx] >> 7) & 0xFFu;
            cnt = (e >= 96u && e <= 160u) ? 1 : 0;
        }
    }
    sd[tid] = orv; sc[tid] = cnt;
    __syncthreads();
    #pragma unroll
    for (int off = 128; off > 0; off >>= 1){
        if (tid < off){ sd[tid] |= sd[tid+off]; sc[tid] += sc[tid+off]; }
        __syncthreads();
    }
    if (tid == 0){
        if (sd[0]) atomicOr(&raw[0], sd[0]);
        if (sc[0]) atomicAdd(&raw[1], sc[0]);
    }
}

__global__ void finalize_kernel(const int* __restrict__ raw, int* __restrict__ flags){
    flags[0] = (raw[0] == 0) ? 1 : 0;
    flags[1] = (raw[1]*2 > 4096) ? 1 : 0;
}

__device__ __forceinline__ int load_src(const int* ei, int e, int E, int is64){
    return is64 ? ei[2*e] : ei[e];
}
__device__ __forceinline__ int load_dst(const int* ei, int e, int E, int is64){
    return is64 ? ei[2*(E + e)] : ei[E + e];
}
__device__ __forceinline__ float loadf(const void* base, size_t idx, int isbf){
    return isbf ? __bfloat162float(((const bf16*)base)[idx]) : ((const float*)base)[idx];
}

// ---------- CSR build ----------
__global__ void count_kernel(const int* __restrict__ ei, const int* __restrict__ flags,
                             int* __restrict__ counts, int E, int N){
    int e = blockIdx.x*256 + threadIdx.x;
    if (e < E){
        int d = load_dst(ei, e, E, flags[0]);
        if ((unsigned)d < (unsigned)N) atomicAdd(&counts[d], 1);
    }
}

__global__ void partial_kernel(const int* __restrict__ counts, int* __restrict__ partial, int N){
    __shared__ int sd[256];
    int tid = threadIdx.x;
    int i = blockIdx.x*256 + tid;
    sd[tid] = (i < N) ? counts[i] : 0;
    __syncthreads();
    #pragma unroll
    for (int off = 128; off > 0; off >>= 1){
        if (tid < off) sd[tid] += sd[tid+off];
        __syncthreads();
    }
    if (tid == 0) partial[blockIdx.x] = sd[0];
}

__global__ void scanp_kernel(const int* __restrict__ partial, int* __restrict__ blockoff, int nb){
    __shared__ int sd[256];
    int tid = threadIdx.x;
    int v = (tid < nb) ? partial[tid] : 0;
    sd[tid] = v;
    __syncthreads();
    #pragma unroll
    for (int off = 1; off < 256; off <<= 1){
        int t = (tid >= off) ? sd[tid-off] : 0;
        __syncthreads();
        sd[tid] += t;
        __syncthreads();
    }
    if (tid < nb) blockoff[tid] = sd[tid] - v;
}

// offsets + cursor + dinv (fused)
__global__ void offsets_kernel(const int* __restrict__ counts, const int* __restrict__ blockoff,
                               int* __restrict__ offsets, int* __restrict__ cursor,
                               float* __restrict__ dinv, int N){
    __shared__ int sd[256];
    int tid = threadIdx.x;
    int i = blockIdx.x*256 + tid;
    int v = (i < N) ? counts[i] : 0;
    sd[tid] = v;
    __syncthreads();
    #pragma unroll
    for (int off = 1; off < 256; off <<= 1){
        int t = (tid >= off) ? sd[tid-off] : 0;
        __syncthreads();
        sd[tid] += t;
        __syncthreads();
    }
    if (i < N){
        int o = blockoff[blockIdx.x] + sd[tid] - v;
        offsets[i] = o;
        cursor[i]  = o;
        double d = (double)(v + 1);
        if (d < 1.0) d = 1.0;
        dinv[i] = (float)(1.0 / sqrt(d));
    }
}

__global__ void scatter_kernel(const int* __restrict__ ei, const int* __restrict__ flags,
                               int* __restrict__ cursor, int* __restrict__ csr, int E, int N){
    int e = blockIdx.x*256 + threadIdx.x;
    if (e < E){
        int is64 = flags[0];
        int d = load_dst(ei, e, E, is64);
        int s = load_src(ei, e, E, is64);
        if ((unsigned)d < (unsigned)N){
            int pos = atomicAdd(&cursor[d], 1);
            if ((unsigned)pos < (unsigned)E) csr[pos] = s;
        }
    }
}

// ---------- W prep: W^T split into bf16 hi/lo. 256 blocks; thread = one output element ----------
__global__ __launch_bounds__(256) void wprep_kernel(const void* __restrict__ W0, const void* __restrict__ W1,
                                                    const void* __restrict__ W2, const void* __restrict__ W3,
                                                    const int* __restrict__ flags,
                                                    unsigned short* __restrict__ WThi, unsigned short* __restrict__ WTlo){
    int l = blockIdx.x >> 6;
    const void* Wl = l == 0 ? W0 : l == 1 ? W1 : l == 2 ? W2 : W3;
    int isbf = flags[1];
    int o = (blockIdx.x & 63)*256 + threadIdx.x;   // o = c*128 + k
    int c = o >> 7, k = o & 127;
    unsigned short hi, lo;
    if (isbf){
        hi = ((const unsigned short*)Wl)[k*128 + c]; lo = 0;
    } else {
        float w = ((const float*)Wl)[k*128 + c];
        hi = f2b(w);
        lo = f2b(w - b2f(hi));
    }
    WThi[(size_t)l*16384 + o] = hi;
    WTlo[(size_t)l*16384 + o] = lo;
}

// ---------- GEMM: XW[N,128] = X[N,128] @ W[128,128] on matrix cores; OUTPUT ALWAYS fp16.
// fp32 path: bf16x2 split (hi/lo), 3 MFMA passes. bf16 path: single pass.
// Fragment recipe (verified m92/m97): row-major A + B^T tiles; lane reads row (lane&15),
// 8 contiguous k at 8*(lane>>4); C/D: col=lane&15, row=4*(lane>>4)+reg.
__global__ __launch_bounds__(256) void gemm_kernel(const void* __restrict__ X,
                                                   const unsigned short* __restrict__ WThi,
                                                   const unsigned short* __restrict__ WTlo,
                                                   const int* __restrict__ flags,
                                                   __half* __restrict__ Y, int N){
    __shared__ __align__(16) unsigned short xhi[64*136];
    __shared__ __align__(16) unsigned short xlo[64*136];
    __shared__ __align__(16) unsigned short bh[128*40];   // per-k0 chunk: 128 rows x 32 k (+8 pad)
    __shared__ __align__(16) unsigned short bl[128*40];
    int tid = threadIdx.x;
    int r0 = blockIdx.x*64;
    int isbf = flags[1];

    if (isbf){
        for (int i = tid; i < 64*16; i += 256){
            int r = i >> 4, sg = i & 15;
            float4 v = make_float4(0.f,0.f,0.f,0.f);
            if (r0 + r < N) v = ((const float4*)X)[(size_t)(r0+r)*16 + sg];
            *(float4*)&xhi[r*136 + sg*8] = v;
        }
    } else {
        for (int i = tid; i < 64*32; i += 256){
            int r = i >> 5, f4 = i & 31;
            float4 v = make_float4(0.f,0.f,0.f,0.f);
            if (r0 + r < N) v = ((const float4*)X)[(size_t)(r0+r)*32 + f4];
            ushort4 hv, lv;
            hv.x = f2b(v.x); lv.x = f2b(v.x - b2f(hv.x));
            hv.y = f2b(v.y); lv.y = f2b(v.y - b2f(hv.y));
            hv.z = f2b(v.z); lv.z = f2b(v.z - b2f(hv.z));
            hv.w = f2b(v.w); lv.w = f2b(v.w - b2f(hv.w));
            *(ushort4*)&xhi[r*136 + f4*4] = hv;
            *(ushort4*)&xlo[r*136 + f4*4] = lv;
        }
    }

    int wv = tid >> 6, lane = tid & 63;
    int lq = lane & 15, lh = lane >> 4;

    f32x4 acc[8];
    #pragma unroll
    for (int i = 0; i < 8; i++){
        #pragma unroll
        for (int e = 0; e < 4; e++) acc[i][e] = 0.f;
    }

    for (int k0 = 0; k0 < 4; k0++){
        __syncthreads();   // protect b-chunk from previous iteration's readers; k0=0: cover x staging
        for (int i = tid; i < 512; i += 256){
            int rr = i >> 2, sg = i & 3;
            *(float4*)&bh[rr*40 + sg*8] = *(const float4*)&WThi[rr*128 + k0*32 + sg*8];
        }
        if (!isbf){
            for (int i = tid; i < 512; i += 256){
                int rr = i >> 2, sg = i & 3;
                *(float4*)&bl[rr*40 + sg*8] = *(const float4*)&WTlo[rr*128 + k0*32 + sg*8];
            }
        }
        __syncthreads();

        short8 ah = *reinterpret_cast<const short8*>(&xhi[(wv*16 + lq)*136 + k0*32 + lh*8]);
        if (isbf){
            #pragma unroll
            for (int nt = 0; nt < 8; nt++){
                short8 bhf = *reinterpret_cast<const short8*>(&bh[(nt*16 + lq)*40 + lh*8]);
                acc[nt] = __builtin_amdgcn_mfma_f32_16x16x32_bf16(ah, bhf, acc[nt], 0, 0, 0);
            }
        } else {
            short8 al = *reinterpret_cast<const short8*>(&xlo[(wv*16 + lq)*136 + k0*32 + lh*8]);
            #pragma unroll
            for (int nt = 0; nt < 8; nt++){
                short8 bhf = *reinterpret_cast<const short8*>(&bh[(nt*16 + lq)*40 + lh*8]);
                short8 blf = *reinterpret_cast<const short8*>(&bl[(nt*16 + lq)*40 + lh*8]);
                acc[nt] = __builtin_amdgcn_mfma_f32_16x16x32_bf16(ah, bhf, acc[nt], 0, 0, 0);
                acc[nt] = __builtin_amdgcn_mfma_f32_16x16x32_bf16(al, bhf, acc[nt], 0, 0, 0);
                acc[nt] = __builtin_amdgcn_mfma_f32_16x16x32_bf16(ah, blf, acc[nt], 0, 0, 0);
            }
        }
    }

    #pragma unroll
    for (int nt = 0; nt < 8; nt++){
        #pragma unroll
        for (int i = 0; i < 4; i++){
            int row = r0 + wv*16 + lh*4 + i;
            if (row < N) Y[(size_t)row*128 + nt*16 + lq] = __float2half(acc[nt][i]);
        }
    }
}

// ---------- aggregation: one wave per dst row (R0 full-wave structure, proven fastest).
// XW is fp16: one row = 256B = 64 lanes x 4B -> ONE VMEM instruction per edge.
// fp32 accumulate; bias/H-store dtype per flag. ----------
__global__ __launch_bounds__(256) void agg_kernel(const unsigned* __restrict__ XWh, const float* __restrict__ dinv,
                                                  const int* __restrict__ offsets, const int* __restrict__ counts,
                                                  const int* __restrict__ csr, const void* __restrict__ bias,
                                                  void* __restrict__ Hout, const int* __restrict__ flags, int N){
    int wave = threadIdx.x >> 6;
    int lane = threadIdx.x & 63;
    int n = blockIdx.x*4 + wave;
    if (n >= N) return;
    int isbf = flags[1];

    float dn = dinv[n];
    float sw = dn*dn;

    float2 sf = h2f2(XWh[(size_t)n*64 + lane]);   // features 2*lane, 2*lane+1
    float accx = sf.x*sw, accy = sf.y*sw;

    int j0 = offsets[n], cnt = counts[n];
    for (int base = 0; base < cnt; base += 64){
        int m = cnt - base; if (m > 64) m = 64;
        int s_l = 0; float w_l = 0.f;
        if (lane < m){
            int s = csr[j0 + base + lane];
            if ((unsigned)s < (unsigned)N){ s_l = s; w_l = dinv[s]*dn; }
        }
        int j = 0;
        for (; j + 4 <= m; j += 4){
            int   s0 = __shfl(s_l, j),   s1 = __shfl(s_l, j+1), s2 = __shfl(s_l, j+2), s3 = __shfl(s_l, j+3);
            float w0 = __shfl(w_l, j),   w1 = __shfl(w_l, j+1), w2 = __shfl(w_l, j+2), w3 = __shfl(w_l, j+3);
            unsigned u0 = XWh[(size_t)s0*64 + lane];
            unsigned u1 = XWh[(size_t)s1*64 + lane];
            unsigned u2 = XWh[(size_t)s2*64 + lane];
            unsigned u3 = XWh[(size_t)s3*64 + lane];
            float2 f0 = h2f2(u0), f1 = h2f2(u1), f2 = h2f2(u2), f3 = h2f2(u3);
            accx += f0.x*w0; accy += f0.y*w0;
            accx += f1.x*w1; accy += f1.y*w1;
            accx += f2.x*w2; accy += f2.y*w2;
            accx += f3.x*w3; accy += f3.y*w3;
        }
        for (; j < m; ++j){
            int   s = __shfl(s_l, j);
            float w = __shfl(w_l, j);
            float2 f = h2f2(XWh[(size_t)s*64 + lane]);
            accx += f.x*w; accy += f.y*w;
        }
    }

    accx = elu_f(accx + loadf(bias, 2*lane,     isbf));
    accy = elu_f(accy + loadf(bias, 2*lane + 1, isbf));
    if (isbf){
        ushort2 o;
        o.x = f2b(accx); o.y = f2b(accy);
        *(ushort2*)((bf16*)Hout + (size_t)n*128 + lane*2) = o;
    } else {
        *(float2*)((float*)Hout + (size_t)n*128 + lane*2) = make_float2(accx, accy);
    }
}

// ---------- MLP head (only Wm2/bm2 survive the reference's reassignment bug) ----------
__global__ __launch_bounds__(256) void mlp_kernel(void* __restrict__ dout, const void* __restrict__ Wm,
                                                  const void* __restrict__ bm, const int* __restrict__ flags, int N){
    __shared__ float ws_[1280];
    __shared__ __align__(16) float hs[16][136];
    int tid = threadIdx.x;
    int isbf = flags[1];
    for (int i = tid; i < 1280; i += 256) ws_[i] = loadf(Wm, i, isbf);

    int r = tid >> 4, c = tid & 15;
    int row = blockIdx.x*16 + r;
    if (isbf){
        if (row < N){
            float4 v = ((const float4*)dout)[(size_t)row*16 + c];   // 8 bf16
            const unsigned short* u = (const unsigned short*)&v;
            #pragma unroll
            for (int j = 0; j < 8; j++) hs[r][c*8 + j] = b2f(u[j]);
        }
    } else {
        if (row < N){
            float4 v0 = ((const float4*)dout)[(size_t)row*32 + c*2];
            float4 v1 = ((const float4*)dout)[(size_t)row*32 + c*2 + 1];
            *(float4*)&hs[r][c*8]     = v0;
            *(float4*)&hs[r][c*8 + 4] = v1;
        }
    }
    __syncthreads();
    if (row < N && c < 10){
        float acc = 0.f;
        #pragma unroll 8
        for (int k = 0; k < 128; k++) acc += hs[r][k]*ws_[k*10 + c];
        acc += loadf(bm, c, isbf);
        float res = elu_f(acc);
        if (isbf){
            ((bf16*)dout)[(size_t)N*128 + (size_t)row*10 + c] = __float2bfloat16(res);
        } else {
            ((float*)dout)[(size_t)N*128 + (size_t)row*10 + c] = res;
        }
    }
}

static inline char* alignup(char* p, size_t a){ return (char*)(((uintptr_t)p + a - 1) & ~(a - 1)); }

extern "C" void kernel_launch(void* const* d_in, const int* in_sizes, int n_in,
                              void* d_out, int out_size, void* d_ws, size_t ws_size,
                              hipStream_t stream){
    const void* x  = d_in[0];
    const int*  ei = (const int*)d_in[1];
    const void* W[4] = {d_in[2], d_in[4], d_in[6], d_in[8]};
    const void* B[4] = {d_in[3], d_in[5], d_in[7], d_in[9]};
    const void* Wm2 = d_in[12];
    const void* bm2 = d_in[13];

    int N = in_sizes[0] / 128;
    int E = in_sizes[1] / 2;

    char* p = (char*)d_ws;
    int*   flags    = (int*)p;
    int*   raw      = flags + 2;                   p = alignup(p + 4*sizeof(int), 256);
    float* dinv     = (float*)p;                   p = alignup(p + (size_t)N*4, 256);
    int*   counts   = (int*)p;                     p = alignup(p + (size_t)N*4, 256);
    int*   offsets  = (int*)p;                     p = alignup(p + (size_t)N*4, 256);
    int*   cursor   = (int*)p;                     p = alignup(p + (size_t)N*4, 256);
    int*   partial  = (int*)p;                     p = alignup(p + 256*4, 256);
    int*   blockoff = (int*)p;                     p = alignup(p + 256*4, 256);
    int*   csr      = (int*)p;                     p = alignup(p + (size_t)E*4, 256);
    __half* xw      = (__half*)p;                  p = alignup(p + (size_t)N*128*4, 256);  // fp16 used; slot kept fp32-sized
    unsigned short* WThi = (unsigned short*)p;     p = alignup(p + (size_t)4*16384*2, 256);
    unsigned short* WTlo = (unsigned short*)p;     p = alignup(p + (size_t)4*16384*2, 256);

    int nb = (N + 255)/256;   // 196 <= 256: single-block top scan valid

    hipMemsetAsync(flags, 0, 4*sizeof(int), stream);
    hipMemsetAsync(counts, 0, (size_t)N*sizeof(int), stream);
    detect_part_kernel<<<128, 256, 0, stream>>>((const unsigned*)ei, 2*E, (const unsigned*)x, N*128/2, raw);
    finalize_kernel   <<<1, 1, 0, stream>>>(raw, flags);
    wprep_kernel  <<<256, 256, 0, stream>>>(W[0], W[1], W[2], W[3], flags, WThi, WTlo);
    count_kernel  <<<(E + 255)/256, 256, 0, stream>>>(ei, flags, counts, E, N);
    partial_kernel<<<nb, 256, 0, stream>>>(counts, partial, N);
    scanp_kernel  <<<1, 256, 0, stream>>>(partial, blockoff, nb);
    offsets_kernel<<<nb, 256, 0, stream>>>(counts, blockoff, offsets, cursor, dinv, N);
    scatter_kernel<<<(E + 255)/256, 256, 0, stream>>>(ei, flags, cursor, csr, E, N);

    for (int l = 0; l < 4; ++l){
        const void* Xin = (l == 0) ? x : (const void*)d_out;
        gemm_kernel<<<(N + 63)/64, 256, 0, stream>>>(Xin, WThi + (size_t)l*16384, WTlo + (size_t)l*16384, flags, xw, N);
        agg_kernel <<<(N + 3)/4, 256, 0, stream>>>((const unsigned*)xw, dinv, offsets, counts, csr, B[l], d_out, flags, N);
    }
    mlp_kernel<<<((N*16) + 255)/256, 256, 0, stream>>>(d_out, Wm2, bm2, flags, N);
}